// Round 1
// baseline (251.906 us; speedup 1.0000x reference)
//
#include <hip/hip_runtime.h>
#include <hip/hip_bf16.h>
#include <stdint.h>

#define T_TOK 16384
#define D_DIM 1024
#define E_EXP 64
#define R_RANK 8
#define SCALE 0.125f

typedef __attribute__((ext_vector_type(8))) __bf16 bf16x8;
typedef __attribute__((ext_vector_type(4))) float f32x4;

__device__ __forceinline__ uint16_t bf16_rne(float f) {
  union { float f; uint32_t u; } v; v.f = f;
  return (uint16_t)((v.u + 0x7fffu + ((v.u >> 16) & 1u)) >> 16);
}

__device__ __forceinline__ void gld_lds16(const void* g, void* l) {
  __builtin_amdgcn_global_load_lds(
      (const __attribute__((address_space(1))) uint32_t*)g,
      (__attribute__((address_space(3))) uint32_t*)l, 16, 0, 0);
}

// ---------------- prep: W [K][N] f32 -> Wt [N][K] bf16 (transposed) ----------
__global__ __launch_bounds__(256) void k_prep_w(const float* __restrict__ W,
                                                uint16_t* __restrict__ Wt) {
  __shared__ float tile[32][33];
  const int t = threadIdx.x;
  const int r0 = blockIdx.y * 32, c0 = blockIdx.x * 32;
  const int r = t >> 3, c = (t & 7) * 4;
  float4 v = *(const float4*)(W + (size_t)(r0 + r) * D_DIM + c0 + c);
  tile[r][c + 0] = v.x; tile[r][c + 1] = v.y;
  tile[r][c + 2] = v.z; tile[r][c + 3] = v.w;
  __syncthreads();
  const int n = t >> 3;           // output row (= column of W)
  const int kk = (t & 7) * 4;     // k offset
  ushort4 o;
  o.x = bf16_rne(tile[kk + 0][n]);
  o.y = bf16_rne(tile[kk + 1][n]);
  o.z = bf16_rne(tile[kk + 2][n]);
  o.w = bf16_rne(tile[kk + 3][n]);
  *(ushort4*)(Wt + (size_t)(c0 + n) * D_DIM + r0 + kk) = o;
}

// ---------------- prep: B [E][R][N] f32 -> Bb [E][N][R] bf16 (transposed) ----
__global__ __launch_bounds__(256) void k_prep_b(const float* __restrict__ B,
                                                uint16_t* __restrict__ Bb) {
  const int idx = blockIdx.x * 256 + threadIdx.x;   // e*1024 + n
  const int e = idx >> 10, n = idx & 1023;
  const float* src = B + (size_t)e * (R_RANK * D_DIM) + n;
  ushort4 o0, o1;
  o0.x = bf16_rne(src[0 * D_DIM]); o0.y = bf16_rne(src[1 * D_DIM]);
  o0.z = bf16_rne(src[2 * D_DIM]); o0.w = bf16_rne(src[3 * D_DIM]);
  o1.x = bf16_rne(src[4 * D_DIM]); o1.y = bf16_rne(src[5 * D_DIM]);
  o1.z = bf16_rne(src[6 * D_DIM]); o1.w = bf16_rne(src[7 * D_DIM]);
  *(ushort4*)(Bb + (size_t)idx * 8) = o0;
  *(ushort4*)(Bb + (size_t)idx * 8 + 4) = o1;
}

// ---------------- prep: x -> bf16 copy + xa[t][r] = sum_d x[t,d]*A[l_t][d,r] -
__global__ __launch_bounds__(256) void k_prep_x(const float* __restrict__ x,
                                                const int* __restrict__ labels,
                                                const float* __restrict__ A,
                                                uint16_t* __restrict__ xb,
                                                float* __restrict__ xa) {
  const int wid = threadIdx.x >> 6, lane = threadIdx.x & 63;
  const int tok = blockIdx.x * 4 + wid;
  const int lbl = labels[tok];
  const float* xrow = x + (size_t)tok * D_DIM;
  const float* Ae = A + (size_t)lbl * (D_DIM * R_RANK);
  float a0 = 0, a1 = 0, a2 = 0, a3 = 0, a4 = 0, a5 = 0, a6 = 0, a7 = 0;
#pragma unroll
  for (int it = 0; it < 4; ++it) {
    const int d = it * 256 + lane * 4;
    float4 xv = *(const float4*)(xrow + d);
    ushort4 o;
    o.x = bf16_rne(xv.x); o.y = bf16_rne(xv.y);
    o.z = bf16_rne(xv.z); o.w = bf16_rne(xv.w);
    *(ushort4*)(xb + (size_t)tok * D_DIM + d) = o;
#pragma unroll
    for (int i = 0; i < 4; ++i) {
      const float xs = (i == 0) ? xv.x : (i == 1) ? xv.y : (i == 2) ? xv.z : xv.w;
      const float* ar = Ae + (size_t)(d + i) * R_RANK;
      float4 p0 = *(const float4*)(ar);
      float4 p1 = *(const float4*)(ar + 4);
      a0 += xs * p0.x; a1 += xs * p0.y; a2 += xs * p0.z; a3 += xs * p0.w;
      a4 += xs * p1.x; a5 += xs * p1.y; a6 += xs * p1.z; a7 += xs * p1.w;
    }
  }
#pragma unroll
  for (int off = 32; off >= 1; off >>= 1) {
    a0 += __shfl_xor(a0, off); a1 += __shfl_xor(a1, off);
    a2 += __shfl_xor(a2, off); a3 += __shfl_xor(a3, off);
    a4 += __shfl_xor(a4, off); a5 += __shfl_xor(a5, off);
    a6 += __shfl_xor(a6, off); a7 += __shfl_xor(a7, off);
  }
  if (lane == 0) {
    float4 q0 = {a0, a1, a2, a3}, q1 = {a4, a5, a6, a7};
    *(float4*)(xa + (size_t)tok * 8) = q0;
    *(float4*)(xa + (size_t)tok * 8 + 4) = q1;
  }
}

// ---------------- main GEMM: out = xb @ Wt^T + bias + SCALE * xa @ Bb[l] -----
// 128x128 tile, BK=32, 4 waves (2x2), each wave 64x64 = 4x4 16x16x32 frags.
__global__ __launch_bounds__(256) void k_gemm(const uint16_t* __restrict__ xb,
                                              const uint16_t* __restrict__ Wt,
                                              const uint16_t* __restrict__ Bb,
                                              const float* __restrict__ xa,
                                              const int* __restrict__ labels,
                                              const float* __restrict__ bias,
                                              float* __restrict__ out) {
  __shared__ __align__(16) uint16_t As[128 * 32];  // [m][k]
  __shared__ __align__(16) uint16_t Bs[128 * 32];  // [n][k]
  __shared__ __align__(16) float xas[128][8];
  __shared__ int lbls[128];

  const int t = threadIdx.x;
  const int wid = t >> 6, lane = t & 63;

  // XCD-aware bijective swizzle (nwg = 1024, 1024 % 8 == 0)
  const int bid = blockIdx.x;
  const int sid = (bid & 7) * 128 + (bid >> 3);
  const int m0 = (sid >> 3) * 128;
  const int n0 = (sid & 7) * 128;

  // stage per-tile token metadata
  if (t < 128) lbls[t] = labels[m0 + t];
  {
    const int r = t >> 1, c = (t & 1) * 4;
    *(float4*)&xas[r][c] = *(const float4*)(xa + (size_t)(m0 + r) * 8 + c);
  }
  __syncthreads();

  f32x4 acc[4][4] = {};
  const int wr = wid >> 1, wc = wid & 1;
  const int row_h = t >> 2;        // 0..63 (row within half-tile)
  const int seg = (t & 3) * 8;     // k element offset of this thread's 16B

  const int fr = lane & 15, fq = lane >> 4;

  for (int kt = 0; kt < 32; ++kt) {
    const int k0 = kt * 32;
    uint16_t* ldsA = As + wid * 512;   // wave-uniform LDS base
    uint16_t* ldsB = Bs + wid * 512;
    gld_lds16(xb + (size_t)(m0 + row_h) * D_DIM + k0 + seg, ldsA);
    gld_lds16(xb + (size_t)(m0 + 64 + row_h) * D_DIM + k0 + seg, ldsA + 2048);
    gld_lds16(Wt + (size_t)(n0 + row_h) * D_DIM + k0 + seg, ldsB);
    gld_lds16(Wt + (size_t)(n0 + 64 + row_h) * D_DIM + k0 + seg, ldsB + 2048);
    __syncthreads();

    bf16x8 af[4], bfr[4];
#pragma unroll
    for (int i = 0; i < 4; ++i) {
      af[i]  = *(const bf16x8*)(As + (wr * 64 + i * 16 + fr) * 32 + fq * 8);
      bfr[i] = *(const bf16x8*)(Bs + (wc * 64 + i * 16 + fr) * 32 + fq * 8);
    }
#pragma unroll
    for (int i = 0; i < 4; ++i)
#pragma unroll
      for (int j = 0; j < 4; ++j)
        acc[i][j] = __builtin_amdgcn_mfma_f32_16x16x32_bf16(af[i], bfr[j], acc[i][j], 0, 0, 0);
    __syncthreads();
  }

  // epilogue: out = acc + bias + SCALE * (xa . Bb[lbl][n][:])
  float bv[4];
#pragma unroll
  for (int j = 0; j < 4; ++j) bv[j] = bias[n0 + wc * 64 + j * 16 + fr];

#pragma unroll
  for (int i = 0; i < 4; ++i) {
#pragma unroll
    for (int jj = 0; jj < 4; ++jj) {
      const int ml = wr * 64 + i * 16 + fq * 4 + jj;   // C/D row mapping
      const int tokrow = m0 + ml;
      const int lbl = lbls[ml];
      const float xv0 = xas[ml][0], xv1 = xas[ml][1], xv2 = xas[ml][2], xv3 = xas[ml][3];
      const float xv4 = xas[ml][4], xv5 = xas[ml][5], xv6 = xas[ml][6], xv7 = xas[ml][7];
#pragma unroll
      for (int j = 0; j < 4; ++j) {
        const int n = n0 + wc * 64 + j * 16 + fr;      // C/D col mapping
        const bf16x8 bb = *(const bf16x8*)(Bb + ((size_t)lbl * D_DIM + n) * 8);
        float dot = xv0 * (float)bb[0] + xv1 * (float)bb[1] + xv2 * (float)bb[2] +
                    xv3 * (float)bb[3] + xv4 * (float)bb[4] + xv5 * (float)bb[5] +
                    xv6 * (float)bb[6] + xv7 * (float)bb[7];
        out[(size_t)tokrow * D_DIM + n] = acc[i][j][jj] + bv[j] + SCALE * dot;
      }
    }
  }
}

extern "C" void kernel_launch(void* const* d_in, const int* in_sizes, int n_in,
                              void* d_out, int out_size, void* d_ws, size_t ws_size,
                              hipStream_t stream) {
  (void)in_sizes; (void)n_in; (void)out_size; (void)ws_size;
  const float* x      = (const float*)d_in[0];
  const int*   labels = (const int*)d_in[1];
  const float* W      = (const float*)d_in[2];
  const float* A      = (const float*)d_in[3];
  const float* B      = (const float*)d_in[4];
  const float* bias   = (const float*)d_in[5];
  float* out = (float*)d_out;

  uint8_t* ws = (uint8_t*)d_ws;
  uint16_t* xb = (uint16_t*)ws;                          // 33,554,432 B
  uint16_t* Wt = (uint16_t*)(ws + (size_t)33554432);     //  2,097,152 B
  uint16_t* Bb = (uint16_t*)(ws + (size_t)35651584);     //  1,048,576 B
  float*    xa = (float*)   (ws + (size_t)36700160);     //    524,288 B

  k_prep_w<<<dim3(32, 32), 256, 0, stream>>>(W, Wt);
  k_prep_b<<<256, 256, 0, stream>>>(B, Bb);
  k_prep_x<<<4096, 256, 0, stream>>>(x, labels, A, xb, xa);
  k_gemm<<<1024, 256, 0, stream>>>(xb, Wt, Bb, xa, labels, bias, out);
}

// Round 2
// 199.211 us; speedup vs baseline: 1.2645x; 1.2645x over previous
//
#include <hip/hip_runtime.h>
#include <hip/hip_bf16.h>
#include <stdint.h>

#define T_TOK 16384
#define D_DIM 1024
#define E_EXP 64
#define R_RANK 8
#define SCALE 0.125f

typedef __attribute__((ext_vector_type(8))) __bf16 bf16x8;
typedef __attribute__((ext_vector_type(4))) float f32x4;

__device__ __forceinline__ uint16_t bf16_rne(float f) {
  union { float f; uint32_t u; } v; v.f = f;
  return (uint16_t)((v.u + 0x7fffu + ((v.u >> 16) & 1u)) >> 16);
}

__device__ __forceinline__ float bf16_to_f(uint16_t h) {
  union { uint32_t u; float f; } v; v.u = ((uint32_t)h) << 16;
  return v.f;
}

__device__ __forceinline__ void gld_lds16(const void* g, void* l) {
  __builtin_amdgcn_global_load_lds(
      (const __attribute__((address_space(1))) uint32_t*)g,
      (__attribute__((address_space(3))) uint32_t*)l, 16, 0, 0);
}

// ---------------- prep: W [K][N] f32 -> Wt [N][K] bf16 (transposed) ----------
__global__ __launch_bounds__(256) void k_prep_w(const float* __restrict__ W,
                                                uint16_t* __restrict__ Wt) {
  __shared__ float tile[32][33];
  const int t = threadIdx.x;
  const int r0 = blockIdx.y * 32, c0 = blockIdx.x * 32;
  const int r = t >> 3, c = (t & 7) * 4;
  float4 v = *(const float4*)(W + (size_t)(r0 + r) * D_DIM + c0 + c);
  tile[r][c + 0] = v.x; tile[r][c + 1] = v.y;
  tile[r][c + 2] = v.z; tile[r][c + 3] = v.w;
  __syncthreads();
  const int n = t >> 3;           // output row (= column of W)
  const int kk = (t & 7) * 4;     // k offset
  ushort4 o;
  o.x = bf16_rne(tile[kk + 0][n]);
  o.y = bf16_rne(tile[kk + 1][n]);
  o.z = bf16_rne(tile[kk + 2][n]);
  o.w = bf16_rne(tile[kk + 3][n]);
  *(ushort4*)(Wt + (size_t)(c0 + n) * D_DIM + r0 + kk) = o;
}

// ---------------- prep: B [E][R][N] f32 -> Bb [E][N][R] bf16 (transposed) ----
__global__ __launch_bounds__(256) void k_prep_b(const float* __restrict__ B,
                                                uint16_t* __restrict__ Bb) {
  const int idx = blockIdx.x * 256 + threadIdx.x;   // e*1024 + n
  const int e = idx >> 10, n = idx & 1023;
  const float* src = B + (size_t)e * (R_RANK * D_DIM) + n;
  ushort4 o0, o1;
  o0.x = bf16_rne(src[0 * D_DIM]); o0.y = bf16_rne(src[1 * D_DIM]);
  o0.z = bf16_rne(src[2 * D_DIM]); o0.w = bf16_rne(src[3 * D_DIM]);
  o1.x = bf16_rne(src[4 * D_DIM]); o1.y = bf16_rne(src[5 * D_DIM]);
  o1.z = bf16_rne(src[6 * D_DIM]); o1.w = bf16_rne(src[7 * D_DIM]);
  *(ushort4*)(Bb + (size_t)idx * 8) = o0;
  *(ushort4*)(Bb + (size_t)idx * 8 + 4) = o1;
}

// ---------------- prep: A [E][D][R] f32 -> At [E][R][D] bf16 (transposed) ----
__global__ __launch_bounds__(256) void k_prep_a(const float* __restrict__ A,
                                                uint16_t* __restrict__ At) {
  const int idx = blockIdx.x * 256 + threadIdx.x;   // e*1024 + d
  const int e = idx >> 10, d = idx & 1023;
  const float* src = A + (size_t)idx * R_RANK;      // A[e][d][:]
  float4 p0 = *(const float4*)(src);
  float4 p1 = *(const float4*)(src + 4);
  uint16_t* dst = At + (size_t)e * (R_RANK * D_DIM) + d;
  dst[0 * D_DIM] = bf16_rne(p0.x);
  dst[1 * D_DIM] = bf16_rne(p0.y);
  dst[2 * D_DIM] = bf16_rne(p0.z);
  dst[3 * D_DIM] = bf16_rne(p0.w);
  dst[4 * D_DIM] = bf16_rne(p1.x);
  dst[5 * D_DIM] = bf16_rne(p1.y);
  dst[6 * D_DIM] = bf16_rne(p1.z);
  dst[7 * D_DIM] = bf16_rne(p1.w);
}

// ---------------- prep: x -> bf16 copy + xa[t][r] = sum_d x[t,d]*At[l][r][d] -
// One wave per token. x loads float4 (coalesced, HBM); At loads ushort4
// (coalesced 512B/row-chunk, L2-resident 2MB). 8 independent FMA chains.
__global__ __launch_bounds__(256) void k_prep_x(const float* __restrict__ x,
                                                const int* __restrict__ labels,
                                                const uint16_t* __restrict__ At,
                                                uint16_t* __restrict__ xb,
                                                float* __restrict__ xa) {
  const int wid = threadIdx.x >> 6, lane = threadIdx.x & 63;
  const int tok = blockIdx.x * 4 + wid;
  const int lbl = labels[tok];
  const float* xrow = x + (size_t)tok * D_DIM;
  const uint16_t* Ab = At + (size_t)lbl * (R_RANK * D_DIM);
  float acc[8] = {0, 0, 0, 0, 0, 0, 0, 0};
#pragma unroll
  for (int it = 0; it < 4; ++it) {
    const int d = it * 256 + lane * 4;
    float4 xv = *(const float4*)(xrow + d);
    ushort4 o;
    o.x = bf16_rne(xv.x); o.y = bf16_rne(xv.y);
    o.z = bf16_rne(xv.z); o.w = bf16_rne(xv.w);
    *(ushort4*)(xb + (size_t)tok * D_DIM + d) = o;
#pragma unroll
    for (int r = 0; r < 8; ++r) {
      ushort4 av = *(const ushort4*)(Ab + r * D_DIM + d);
      acc[r] += xv.x * bf16_to_f(av.x) + xv.y * bf16_to_f(av.y) +
                xv.z * bf16_to_f(av.z) + xv.w * bf16_to_f(av.w);
    }
  }
#pragma unroll
  for (int off = 32; off >= 1; off >>= 1) {
#pragma unroll
    for (int r = 0; r < 8; ++r) acc[r] += __shfl_xor(acc[r], off);
  }
  if (lane == 0) {
    float4 q0 = {acc[0], acc[1], acc[2], acc[3]};
    float4 q1 = {acc[4], acc[5], acc[6], acc[7]};
    *(float4*)(xa + (size_t)tok * 8) = q0;
    *(float4*)(xa + (size_t)tok * 8 + 4) = q1;
  }
}

// ---------------- main GEMM: out = xb @ Wt^T + bias + SCALE * xa @ Bb[l] -----
// 128x128 tile, BK=32, 4 waves (2x2), each wave 64x64 = 4x4 16x16x32 frags.
// UNCHANGED from round 0 (isolating prep_x change; gemm counters next round).
__global__ __launch_bounds__(256) void k_gemm(const uint16_t* __restrict__ xb,
                                              const uint16_t* __restrict__ Wt,
                                              const uint16_t* __restrict__ Bb,
                                              const float* __restrict__ xa,
                                              const int* __restrict__ labels,
                                              const float* __restrict__ bias,
                                              float* __restrict__ out) {
  __shared__ __align__(16) uint16_t As[128 * 32];  // [m][k]
  __shared__ __align__(16) uint16_t Bs[128 * 32];  // [n][k]
  __shared__ __align__(16) float xas[128][8];
  __shared__ int lbls[128];

  const int t = threadIdx.x;
  const int wid = t >> 6, lane = t & 63;

  // XCD-aware bijective swizzle (nwg = 1024, 1024 % 8 == 0)
  const int bid = blockIdx.x;
  const int sid = (bid & 7) * 128 + (bid >> 3);
  const int m0 = (sid >> 3) * 128;
  const int n0 = (sid & 7) * 128;

  // stage per-tile token metadata
  if (t < 128) lbls[t] = labels[m0 + t];
  {
    const int r = t >> 1, c = (t & 1) * 4;
    *(float4*)&xas[r][c] = *(const float4*)(xa + (size_t)(m0 + r) * 8 + c);
  }
  __syncthreads();

  f32x4 acc[4][4] = {};
  const int wr = wid >> 1, wc = wid & 1;
  const int row_h = t >> 2;        // 0..63 (row within half-tile)
  const int seg = (t & 3) * 8;     // k element offset of this thread's 16B

  const int fr = lane & 15, fq = lane >> 4;

  for (int kt = 0; kt < 32; ++kt) {
    const int k0 = kt * 32;
    uint16_t* ldsA = As + wid * 512;   // wave-uniform LDS base
    uint16_t* ldsB = Bs + wid * 512;
    gld_lds16(xb + (size_t)(m0 + row_h) * D_DIM + k0 + seg, ldsA);
    gld_lds16(xb + (size_t)(m0 + 64 + row_h) * D_DIM + k0 + seg, ldsA + 2048);
    gld_lds16(Wt + (size_t)(n0 + row_h) * D_DIM + k0 + seg, ldsB);
    gld_lds16(Wt + (size_t)(n0 + 64 + row_h) * D_DIM + k0 + seg, ldsB + 2048);
    __syncthreads();

    bf16x8 af[4], bfr[4];
#pragma unroll
    for (int i = 0; i < 4; ++i) {
      af[i]  = *(const bf16x8*)(As + (wr * 64 + i * 16 + fr) * 32 + fq * 8);
      bfr[i] = *(const bf16x8*)(Bs + (wc * 64 + i * 16 + fr) * 32 + fq * 8);
    }
#pragma unroll
    for (int i = 0; i < 4; ++i)
#pragma unroll
      for (int j = 0; j < 4; ++j)
        acc[i][j] = __builtin_amdgcn_mfma_f32_16x16x32_bf16(af[i], bfr[j], acc[i][j], 0, 0, 0);
    __syncthreads();
  }

  // epilogue: out = acc + bias + SCALE * (xa . Bb[lbl][n][:])
  float bv[4];
#pragma unroll
  for (int j = 0; j < 4; ++j) bv[j] = bias[n0 + wc * 64 + j * 16 + fr];

#pragma unroll
  for (int i = 0; i < 4; ++i) {
#pragma unroll
    for (int jj = 0; jj < 4; ++jj) {
      const int ml = wr * 64 + i * 16 + fq * 4 + jj;   // C/D row mapping
      const int tokrow = m0 + ml;
      const int lbl = lbls[ml];
      const float xv0 = xas[ml][0], xv1 = xas[ml][1], xv2 = xas[ml][2], xv3 = xas[ml][3];
      const float xv4 = xas[ml][4], xv5 = xas[ml][5], xv6 = xas[ml][6], xv7 = xas[ml][7];
#pragma unroll
      for (int j = 0; j < 4; ++j) {
        const int n = n0 + wc * 64 + j * 16 + fr;      // C/D col mapping
        const bf16x8 bb = *(const bf16x8*)(Bb + ((size_t)lbl * D_DIM + n) * 8);
        float dot = xv0 * (float)bb[0] + xv1 * (float)bb[1] + xv2 * (float)bb[2] +
                    xv3 * (float)bb[3] + xv4 * (float)bb[4] + xv5 * (float)bb[5] +
                    xv6 * (float)bb[6] + xv7 * (float)bb[7];
        out[(size_t)tokrow * D_DIM + n] = acc[i][j][jj] + bv[j] + SCALE * dot;
      }
    }
  }
}

extern "C" void kernel_launch(void* const* d_in, const int* in_sizes, int n_in,
                              void* d_out, int out_size, void* d_ws, size_t ws_size,
                              hipStream_t stream) {
  (void)in_sizes; (void)n_in; (void)out_size; (void)ws_size;
  const float* x      = (const float*)d_in[0];
  const int*   labels = (const int*)d_in[1];
  const float* W      = (const float*)d_in[2];
  const float* A      = (const float*)d_in[3];
  const float* B      = (const float*)d_in[4];
  const float* bias   = (const float*)d_in[5];
  float* out = (float*)d_out;

  uint8_t* ws = (uint8_t*)d_ws;
  uint16_t* xb = (uint16_t*)ws;                          // 33,554,432 B
  uint16_t* Wt = (uint16_t*)(ws + (size_t)33554432);     //  2,097,152 B
  uint16_t* Bb = (uint16_t*)(ws + (size_t)35651584);     //  1,048,576 B
  float*    xa = (float*)   (ws + (size_t)36700160);     //    524,288 B
  uint16_t* At = (uint16_t*)(ws + (size_t)37224448);     //  1,048,576 B

  k_prep_w<<<dim3(32, 32), 256, 0, stream>>>(W, Wt);
  k_prep_b<<<256, 256, 0, stream>>>(B, Bb);
  k_prep_a<<<256, 256, 0, stream>>>(A, At);
  k_prep_x<<<4096, 256, 0, stream>>>(x, labels, At, xb, xa);
  k_gemm<<<1024, 256, 0, stream>>>(xb, Wt, Bb, xa, labels, bias, out);
}

// Round 3
// 177.180 us; speedup vs baseline: 1.4218x; 1.1243x over previous
//
#include <hip/hip_runtime.h>
#include <hip/hip_bf16.h>
#include <stdint.h>

#define T_TOK 16384
#define D_DIM 1024
#define E_EXP 64
#define R_RANK 8
#define SCALE 0.125f

typedef __attribute__((ext_vector_type(8))) __bf16 bf16x8;
typedef __attribute__((ext_vector_type(4))) float f32x4;

__device__ __forceinline__ uint16_t bf16_rne(float f) {
  union { float f; uint32_t u; } v; v.f = f;
  return (uint16_t)((v.u + 0x7fffu + ((v.u >> 16) & 1u)) >> 16);
}

__device__ __forceinline__ void gld_lds16(const void* g, void* l) {
  __builtin_amdgcn_global_load_lds(
      (const __attribute__((address_space(1))) uint32_t*)g,
      (__attribute__((address_space(3))) uint32_t*)l, 16, 0, 0);
}

// ---------------- prep: W [K][N] f32 -> Wt [N][K] bf16 (transposed) ----------
__global__ __launch_bounds__(256) void k_prep_w(const float* __restrict__ W,
                                                uint16_t* __restrict__ Wt) {
  __shared__ float tile[32][33];
  const int t = threadIdx.x;
  const int r0 = blockIdx.y * 32, c0 = blockIdx.x * 32;
  const int r = t >> 3, c = (t & 7) * 4;
  float4 v = *(const float4*)(W + (size_t)(r0 + r) * D_DIM + c0 + c);
  tile[r][c + 0] = v.x; tile[r][c + 1] = v.y;
  tile[r][c + 2] = v.z; tile[r][c + 3] = v.w;
  __syncthreads();
  const int n = t >> 3;
  const int kk = (t & 7) * 4;
  ushort4 o;
  o.x = bf16_rne(tile[kk + 0][n]);
  o.y = bf16_rne(tile[kk + 1][n]);
  o.z = bf16_rne(tile[kk + 2][n]);
  o.w = bf16_rne(tile[kk + 3][n]);
  *(ushort4*)(Wt + (size_t)(c0 + n) * D_DIM + r0 + kk) = o;
}

// ---------------- prep: B [E][R][N] f32 -> Bb [E][N][R] bf16 (transposed) ----
__global__ __launch_bounds__(256) void k_prep_b(const float* __restrict__ B,
                                                uint16_t* __restrict__ Bb) {
  const int idx = blockIdx.x * 256 + threadIdx.x;
  const int e = idx >> 10, n = idx & 1023;
  const float* src = B + (size_t)e * (R_RANK * D_DIM) + n;
  ushort4 o0, o1;
  o0.x = bf16_rne(src[0 * D_DIM]); o0.y = bf16_rne(src[1 * D_DIM]);
  o0.z = bf16_rne(src[2 * D_DIM]); o0.w = bf16_rne(src[3 * D_DIM]);
  o1.x = bf16_rne(src[4 * D_DIM]); o1.y = bf16_rne(src[5 * D_DIM]);
  o1.z = bf16_rne(src[6 * D_DIM]); o1.w = bf16_rne(src[7 * D_DIM]);
  *(ushort4*)(Bb + (size_t)idx * 8) = o0;
  *(ushort4*)(Bb + (size_t)idx * 8 + 4) = o1;
}

// ---------------- prep: A [E][D][R] f32 -> At [E][R][D] bf16 (transposed) ----
__global__ __launch_bounds__(256) void k_prep_a(const float* __restrict__ A,
                                                uint16_t* __restrict__ At) {
  const int idx = blockIdx.x * 256 + threadIdx.x;
  const int e = idx >> 10, d = idx & 1023;
  const float* src = A + (size_t)idx * R_RANK;
  float4 p0 = *(const float4*)(src);
  float4 p1 = *(const float4*)(src + 4);
  uint16_t* dst = At + (size_t)e * (R_RANK * D_DIM) + d;
  dst[0 * D_DIM] = bf16_rne(p0.x);
  dst[1 * D_DIM] = bf16_rne(p0.y);
  dst[2 * D_DIM] = bf16_rne(p0.z);
  dst[3 * D_DIM] = bf16_rne(p0.w);
  dst[4 * D_DIM] = bf16_rne(p1.x);
  dst[5 * D_DIM] = bf16_rne(p1.y);
  dst[6 * D_DIM] = bf16_rne(p1.z);
  dst[7 * D_DIM] = bf16_rne(p1.w);
}

// ---------------- prep: x -> bf16 copy + xa[t][r] (16B loads, 2 iters) -------
__global__ __launch_bounds__(256) void k_prep_x(const float* __restrict__ x,
                                                const int* __restrict__ labels,
                                                const uint16_t* __restrict__ At,
                                                uint16_t* __restrict__ xb,
                                                float* __restrict__ xa) {
  const int wid = threadIdx.x >> 6, lane = threadIdx.x & 63;
  const int tok = blockIdx.x * 4 + wid;
  const int lbl = labels[tok];
  const float* xrow = x + (size_t)tok * D_DIM;
  const uint16_t* Ab = At + (size_t)lbl * (R_RANK * D_DIM);
  float acc[8] = {0, 0, 0, 0, 0, 0, 0, 0};
#pragma unroll
  for (int it = 0; it < 2; ++it) {
    const int d = it * 512 + lane * 8;
    float4 xv0 = *(const float4*)(xrow + d);
    float4 xv1 = *(const float4*)(xrow + d + 4);
    ushort4 o0, o1;
    o0.x = bf16_rne(xv0.x); o0.y = bf16_rne(xv0.y);
    o0.z = bf16_rne(xv0.z); o0.w = bf16_rne(xv0.w);
    o1.x = bf16_rne(xv1.x); o1.y = bf16_rne(xv1.y);
    o1.z = bf16_rne(xv1.z); o1.w = bf16_rne(xv1.w);
    *(ushort4*)(xb + (size_t)tok * D_DIM + d) = o0;
    *(ushort4*)(xb + (size_t)tok * D_DIM + d + 4) = o1;
#pragma unroll
    for (int r = 0; r < 8; ++r) {
      bf16x8 av = *(const bf16x8*)(Ab + r * D_DIM + d);
      acc[r] += xv0.x * (float)av[0] + xv0.y * (float)av[1] +
                xv0.z * (float)av[2] + xv0.w * (float)av[3] +
                xv1.x * (float)av[4] + xv1.y * (float)av[5] +
                xv1.z * (float)av[6] + xv1.w * (float)av[7];
    }
  }
#pragma unroll
  for (int off = 32; off >= 1; off >>= 1) {
#pragma unroll
    for (int r = 0; r < 8; ++r) acc[r] += __shfl_xor(acc[r], off);
  }
  if (lane == 0) {
    float4 q0 = {acc[0], acc[1], acc[2], acc[3]};
    float4 q1 = {acc[4], acc[5], acc[6], acc[7]};
    *(float4*)(xa + (size_t)tok * 8) = q0;
    *(float4*)(xa + (size_t)tok * 8 + 4) = q1;
  }
}

// ============== main GEMM: 256x256 tile, BK=64, 8-phase schedule =============
// out = xb @ Wt^T + bias + SCALE * xa @ Bb[l]
// 8 waves (2M x 4N), per-wave 128x64 out; LDS 128KiB dbuf; XOR slot swizzle;
// counted vmcnt(4) at K-tile boundaries; raw s_barrier; setprio around MFMA.
#define ABUF_OFF 0
#define BBUF_OFF 65536
#define XAS_OFF  131072
#define LBL_OFF  139264
#define SMEM_BYTES 140288

#define READ_A(bufv, a)                                                        \
  {                                                                            \
    _Pragma("unroll") for (int rm = 0; rm < 4; ++rm)                           \
    _Pragma("unroll") for (int kk = 0; kk < 2; ++kk)                           \
      af[rm][kk] = *(const bf16x8*)(smem + ABUF_OFF + (bufv) * 32768 +         \
                                    (a) * 16384 + (rm * 32 + wr * 16 + fr) * 128 + \
                                    (((kk * 4 + fq) ^ sx) * 16));              \
  }

#define READ_B(bufv, b)                                                        \
  {                                                                            \
    _Pragma("unroll") for (int rn = 0; rn < 2; ++rn)                           \
    _Pragma("unroll") for (int kk = 0; kk < 2; ++kk)                           \
      bfv[rn][kk] = *(const bf16x8*)(smem + BBUF_OFF + (bufv) * 32768 +        \
                                     (b) * 16384 + (rn * 64 + wc * 16 + fr) * 128 + \
                                     (((kk * 4 + fq) ^ sx) * 16));             \
  }

#define MMA(a, b)                                                              \
  {                                                                            \
    __builtin_amdgcn_s_setprio(1);                                             \
    _Pragma("unroll") for (int rm = 0; rm < 4; ++rm)                           \
    _Pragma("unroll") for (int rn = 0; rn < 2; ++rn)                           \
    _Pragma("unroll") for (int kk = 0; kk < 2; ++kk)                           \
      acc[(a) * 4 + rm][(b) * 2 + rn] = __builtin_amdgcn_mfma_f32_16x16x32_bf16( \
          af[rm][kk], bfv[rn][kk], acc[(a) * 4 + rm][(b) * 2 + rn], 0, 0, 0);  \
    __builtin_amdgcn_s_setprio(0);                                             \
  }

#define BAR() __builtin_amdgcn_s_barrier()
#define LGKM0() asm volatile("s_waitcnt lgkmcnt(0)" ::: "memory")

__global__ __launch_bounds__(512, 2) void k_gemm(const uint16_t* __restrict__ xb,
                                                 const uint16_t* __restrict__ Wt,
                                                 const uint16_t* __restrict__ Bb,
                                                 const float* __restrict__ xa,
                                                 const int* __restrict__ labels,
                                                 const float* __restrict__ bias,
                                                 float* __restrict__ out) {
  __shared__ __align__(16) uint8_t smem[SMEM_BYTES];
  const int t = threadIdx.x;
  const int wid = t >> 6, lane = t & 63;
  const int wr = wid >> 2, wc = wid & 3;
  const int fr = lane & 15, fq = lane >> 4;
  const int sx = fr & 7;

  // XCD-aware bijective swizzle (nwg = 256, 256 % 8 == 0)
  const int bid = blockIdx.x;
  const int sid = (bid & 7) * 32 + (bid >> 3);
  const int m0 = (sid >> 2) * 256;
  const int n0 = (sid & 2047 & 3) * 256;

  // stage per-tile token metadata (before pipeline; __syncthreads drains)
  int* lbls = (int*)(smem + LBL_OFF);
  float* xas = (float*)(smem + XAS_OFF);
  if (t < 256) lbls[t] = labels[m0 + t];
  {
    const int r = t >> 1, c = (t & 1) * 4;
    *(float4*)(xas + r * 8 + c) = *(const float4*)(xa + (size_t)(m0 + r) * 8 + c);
  }
  __syncthreads();

  // staging: per call a wave stages 8 rows (1024B linear LDS); 2 calls = half-tile
  const int srow = wid * 8 + (lane >> 3);                    // row in 64-row chunk
  const int sslot = ((lane & 7) ^ ((lane >> 3) & 7)) * 8;    // inverse-swizzled src
  auto stA = [&](int kt, int h) {
    const int buf = kt & 1;
    const uint16_t* g = xb + (size_t)(m0 + h * 128 + srow) * D_DIM + kt * 64 + sslot;
    uint8_t* l = smem + ABUF_OFF + buf * 32768 + h * 16384 + wid * 1024;
    gld_lds16(g, l);
    gld_lds16(g + (size_t)64 * D_DIM, l + 8192);
  };
  auto stB = [&](int kt, int h) {
    const int buf = kt & 1;
    const uint16_t* g = Wt + (size_t)(n0 + h * 128 + srow) * D_DIM + kt * 64 + sslot;
    uint8_t* l = smem + BBUF_OFF + buf * 32768 + h * 16384 + wid * 1024;
    gld_lds16(g, l);
    gld_lds16(g + (size_t)64 * D_DIM, l + 8192);
  };

  f32x4 acc[8][4] = {};
  bf16x8 af[4][2], bfv[2][2];

  // prologue: A0(0), B1(0), A1(0), B0(0), A0(1), B1(1)  (12 loads/thread)
  stA(0, 0); stB(0, 1); stA(0, 1); stB(0, 0); stA(1, 0); stB(1, 1);

  for (int kt = 0; kt < 16; ++kt) {
    const int buf = kt & 1;
    const int kn1 = (kt + 1) & 15, kn2 = (kt + 2) & 15;  // clamp: parity-safe wrap
    asm volatile("s_waitcnt vmcnt(4)" ::: "memory");  // all but newest 2 halves landed
    BAR();
    // phase 0: (A0,B0) — 12 ds_reads; stage A1(kt+1)
    READ_A(buf, 0); READ_B(buf, 0);
    stA(kn1, 1);
    BAR(); LGKM0();
    MMA(0, 0);
    BAR();
    // phase 1: (A0,B1) — 4 ds_reads; stage B0(kt+1)
    READ_B(buf, 1);
    stB(kn1, 0);
    BAR(); LGKM0();
    MMA(0, 1);
    BAR();
    // phase 2: (A1,B1) — 8 ds_reads; stage A0(kt+2) (curr buf; A0 reads done ph0)
    READ_A(buf, 1);
    stA(kn2, 0);
    BAR(); LGKM0();
    MMA(1, 1);
    BAR();
    // phase 3: (A1,B0) — 4 ds_reads; stage B1(kt+2) (curr buf; B1 reads done ph1)
    READ_B(buf, 0);
    stB(kn2, 1);
    BAR(); LGKM0();
    MMA(1, 0);
    BAR();
  }

  // epilogue: out = acc + bias + SCALE * (xa . Bb[lbl][n][:])
  float bv[4];
#pragma unroll
  for (int rn = 0; rn < 4; ++rn) bv[rn] = bias[n0 + rn * 64 + wc * 16 + fr];

#pragma unroll
  for (int rm = 0; rm < 8; ++rm) {
#pragma unroll
    for (int j = 0; j < 4; ++j) {
      const int ml = rm * 32 + wr * 16 + fq * 4 + j;  // C/D row mapping
      const int grow = m0 + ml;
      const int lbl = lbls[ml];
      const float* xv = xas + ml * 8;
      const float x0 = xv[0], x1 = xv[1], x2 = xv[2], x3 = xv[3];
      const float x4 = xv[4], x5 = xv[5], x6 = xv[6], x7 = xv[7];
#pragma unroll
      for (int rn = 0; rn < 4; ++rn) {
        const int n = n0 + rn * 64 + wc * 16 + fr;    // C/D col mapping
        const bf16x8 bb = *(const bf16x8*)(Bb + ((size_t)lbl * D_DIM + n) * 8);
        float dot = x0 * (float)bb[0] + x1 * (float)bb[1] + x2 * (float)bb[2] +
                    x3 * (float)bb[3] + x4 * (float)bb[4] + x5 * (float)bb[5] +
                    x6 * (float)bb[6] + x7 * (float)bb[7];
        out[(size_t)grow * D_DIM + n] = acc[rm][rn][j] + bv[rn] + SCALE * dot;
      }
    }
  }
}

extern "C" void kernel_launch(void* const* d_in, const int* in_sizes, int n_in,
                              void* d_out, int out_size, void* d_ws, size_t ws_size,
                              hipStream_t stream) {
  (void)in_sizes; (void)n_in; (void)out_size; (void)ws_size;
  const float* x      = (const float*)d_in[0];
  const int*   labels = (const int*)d_in[1];
  const float* W      = (const float*)d_in[2];
  const float* A      = (const float*)d_in[3];
  const float* B      = (const float*)d_in[4];
  const float* bias   = (const float*)d_in[5];
  float* out = (float*)d_out;

  uint8_t* ws = (uint8_t*)d_ws;
  uint16_t* xb = (uint16_t*)ws;                          // 33,554,432 B
  uint16_t* Wt = (uint16_t*)(ws + (size_t)33554432);     //  2,097,152 B
  uint16_t* Bb = (uint16_t*)(ws + (size_t)35651584);     //  1,048,576 B
  float*    xa = (float*)   (ws + (size_t)36700160);     //    524,288 B
  uint16_t* At = (uint16_t*)(ws + (size_t)37224448);     //  1,048,576 B

  k_prep_w<<<dim3(32, 32), 256, 0, stream>>>(W, Wt);
  k_prep_b<<<256, 256, 0, stream>>>(B, Bb);
  k_prep_a<<<256, 256, 0, stream>>>(A, At);
  k_prep_x<<<4096, 256, 0, stream>>>(x, labels, At, xb, xa);
  k_gemm<<<256, 512, 0, stream>>>(xb, Wt, Bb, xa, labels, bias, out);
}

// Round 4
// 175.731 us; speedup vs baseline: 1.4335x; 1.0082x over previous
//
#include <hip/hip_runtime.h>
#include <hip/hip_bf16.h>
#include <stdint.h>

#define T_TOK 16384
#define D_DIM 1024
#define E_EXP 64
#define R_RANK 8
#define SCALE 0.125f

typedef __attribute__((ext_vector_type(8))) __bf16 bf16x8;
typedef __attribute__((ext_vector_type(4))) float f32x4;
typedef const __attribute__((address_space(3))) uint8_t* lds_ptr_t;

__device__ __forceinline__ uint16_t bf16_rne(float f) {
  union { float f; uint32_t u; } v; v.f = f;
  return (uint16_t)((v.u + 0x7fffu + ((v.u >> 16) & 1u)) >> 16);
}

__device__ __forceinline__ void gld_lds16(const void* g, void* l) {
  __builtin_amdgcn_global_load_lds(
      (const __attribute__((address_space(1))) uint32_t*)g,
      (__attribute__((address_space(3))) uint32_t*)l, 16, 0, 0);
}

// ---------------- prep: W [K][N] f32 -> Wt [N][K] bf16 (transposed) ----------
__global__ __launch_bounds__(256) void k_prep_w(const float* __restrict__ W,
                                                uint16_t* __restrict__ Wt) {
  __shared__ float tile[32][33];
  const int t = threadIdx.x;
  const int r0 = blockIdx.y * 32, c0 = blockIdx.x * 32;
  const int r = t >> 3, c = (t & 7) * 4;
  float4 v = *(const float4*)(W + (size_t)(r0 + r) * D_DIM + c0 + c);
  tile[r][c + 0] = v.x; tile[r][c + 1] = v.y;
  tile[r][c + 2] = v.z; tile[r][c + 3] = v.w;
  __syncthreads();
  const int n = t >> 3;
  const int kk = (t & 7) * 4;
  ushort4 o;
  o.x = bf16_rne(tile[kk + 0][n]);
  o.y = bf16_rne(tile[kk + 1][n]);
  o.z = bf16_rne(tile[kk + 2][n]);
  o.w = bf16_rne(tile[kk + 3][n]);
  *(ushort4*)(Wt + (size_t)(c0 + n) * D_DIM + r0 + kk) = o;
}

// ---------------- prep: B [E][R][N] f32 -> Bb [E][N][R] bf16 (transposed) ----
__global__ __launch_bounds__(256) void k_prep_b(const float* __restrict__ B,
                                                uint16_t* __restrict__ Bb) {
  const int idx = blockIdx.x * 256 + threadIdx.x;
  const int e = idx >> 10, n = idx & 1023;
  const float* src = B + (size_t)e * (R_RANK * D_DIM) + n;
  ushort4 o0, o1;
  o0.x = bf16_rne(src[0 * D_DIM]); o0.y = bf16_rne(src[1 * D_DIM]);
  o0.z = bf16_rne(src[2 * D_DIM]); o0.w = bf16_rne(src[3 * D_DIM]);
  o1.x = bf16_rne(src[4 * D_DIM]); o1.y = bf16_rne(src[5 * D_DIM]);
  o1.z = bf16_rne(src[6 * D_DIM]); o1.w = bf16_rne(src[7 * D_DIM]);
  *(ushort4*)(Bb + (size_t)idx * 8) = o0;
  *(ushort4*)(Bb + (size_t)idx * 8 + 4) = o1;
}

// ---------------- prep: A [E][D][R] f32 -> At [E][R][D] bf16 (transposed) ----
__global__ __launch_bounds__(256) void k_prep_a(const float* __restrict__ A,
                                                uint16_t* __restrict__ At) {
  const int idx = blockIdx.x * 256 + threadIdx.x;
  const int e = idx >> 10, d = idx & 1023;
  const float* src = A + (size_t)idx * R_RANK;
  float4 p0 = *(const float4*)(src);
  float4 p1 = *(const float4*)(src + 4);
  uint16_t* dst = At + (size_t)e * (R_RANK * D_DIM) + d;
  dst[0 * D_DIM] = bf16_rne(p0.x);
  dst[1 * D_DIM] = bf16_rne(p0.y);
  dst[2 * D_DIM] = bf16_rne(p0.z);
  dst[3 * D_DIM] = bf16_rne(p0.w);
  dst[4 * D_DIM] = bf16_rne(p1.x);
  dst[5 * D_DIM] = bf16_rne(p1.y);
  dst[6 * D_DIM] = bf16_rne(p1.z);
  dst[7 * D_DIM] = bf16_rne(p1.w);
}

// ---------------- prep: x -> bf16 copy + xa[t][r] (16B loads, 2 iters) -------
__global__ __launch_bounds__(256) void k_prep_x(const float* __restrict__ x,
                                                const int* __restrict__ labels,
                                                const uint16_t* __restrict__ At,
                                                uint16_t* __restrict__ xb,
                                                float* __restrict__ xa) {
  const int wid = threadIdx.x >> 6, lane = threadIdx.x & 63;
  const int tok = blockIdx.x * 4 + wid;
  const int lbl = labels[tok];
  const float* xrow = x + (size_t)tok * D_DIM;
  const uint16_t* Ab = At + (size_t)lbl * (R_RANK * D_DIM);
  float acc[8] = {0, 0, 0, 0, 0, 0, 0, 0};
#pragma unroll
  for (int it = 0; it < 2; ++it) {
    const int d = it * 512 + lane * 8;
    float4 xv0 = *(const float4*)(xrow + d);
    float4 xv1 = *(const float4*)(xrow + d + 4);
    ushort4 o0, o1;
    o0.x = bf16_rne(xv0.x); o0.y = bf16_rne(xv0.y);
    o0.z = bf16_rne(xv0.z); o0.w = bf16_rne(xv0.w);
    o1.x = bf16_rne(xv1.x); o1.y = bf16_rne(xv1.y);
    o1.z = bf16_rne(xv1.z); o1.w = bf16_rne(xv1.w);
    *(ushort4*)(xb + (size_t)tok * D_DIM + d) = o0;
    *(ushort4*)(xb + (size_t)tok * D_DIM + d + 4) = o1;
#pragma unroll
    for (int r = 0; r < 8; ++r) {
      bf16x8 av = *(const bf16x8*)(Ab + r * D_DIM + d);
      acc[r] += xv0.x * (float)av[0] + xv0.y * (float)av[1] +
                xv0.z * (float)av[2] + xv0.w * (float)av[3] +
                xv1.x * (float)av[4] + xv1.y * (float)av[5] +
                xv1.z * (float)av[6] + xv1.w * (float)av[7];
    }
  }
#pragma unroll
  for (int off = 32; off >= 1; off >>= 1) {
#pragma unroll
    for (int r = 0; r < 8; ++r) acc[r] += __shfl_xor(acc[r], off);
  }
  if (lane == 0) {
    float4 q0 = {acc[0], acc[1], acc[2], acc[3]};
    float4 q1 = {acc[4], acc[5], acc[6], acc[7]};
    *(float4*)(xa + (size_t)tok * 8) = q0;
    *(float4*)(xa + (size_t)tok * 8 + 4) = q1;
  }
}

// ============== main GEMM: 256x256 tile, BK=64, 8-phase schedule =============
// Same schedule as round 2, but inner-loop LDS reads are inline-asm
// ds_read_b128 (base VGPR + literal offset) so the compiler cannot insert
// vmcnt(0) alias-drains before them; rule-#18 lgkmcnt(0)+sched_barrier(0)
// fences each MFMA cluster; stage issue pinned by sched_barrier(0).
#define ABUF_OFF 0
#define BBUF_OFF 65536
#define XAS_OFF  131072
#define LBL_OFF  139264
#define SMEM_BYTES 140288

#define DSREAD(dst, base, imm)                                                 \
  asm volatile("ds_read_b128 %0, %1 offset:%c2"                                \
               : "=v"(dst) : "v"(base), "i"(imm))

// A-half reads: af[rm][kk] from buffer BUFL, half a. base row = wr*16+fr.
#define READ_A(BUFL, a)                                                        \
  {                                                                            \
    DSREAD(af[0][0], baseA0, (BUFL)*32768 + (a)*16384 + 0 * 4096);             \
    DSREAD(af[0][1], baseA1, (BUFL)*32768 + (a)*16384 + 0 * 4096);             \
    DSREAD(af[1][0], baseA0, (BUFL)*32768 + (a)*16384 + 1 * 4096);             \
    DSREAD(af[1][1], baseA1, (BUFL)*32768 + (a)*16384 + 1 * 4096);             \
    DSREAD(af[2][0], baseA0, (BUFL)*32768 + (a)*16384 + 2 * 4096);             \
    DSREAD(af[2][1], baseA1, (BUFL)*32768 + (a)*16384 + 2 * 4096);             \
    DSREAD(af[3][0], baseA0, (BUFL)*32768 + (a)*16384 + 3 * 4096);             \
    DSREAD(af[3][1], baseA1, (BUFL)*32768 + (a)*16384 + 3 * 4096);             \
  }

// B-half reads: bfv[rn][kk] from buffer BUFL, half b. base row = wc*16+fr.
#define READ_B(BUFL, b)                                                        \
  {                                                                            \
    DSREAD(bfv[0][0], baseB0, (BUFL)*32768 + (b)*16384 + 0 * 8192);            \
    DSREAD(bfv[0][1], baseB1, (BUFL)*32768 + (b)*16384 + 0 * 8192);            \
    DSREAD(bfv[1][0], baseB0, (BUFL)*32768 + (b)*16384 + 1 * 8192);            \
    DSREAD(bfv[1][1], baseB1, (BUFL)*32768 + (b)*16384 + 1 * 8192);            \
  }

#define MMA(a, b)                                                              \
  {                                                                            \
    __builtin_amdgcn_s_setprio(1);                                             \
    _Pragma("unroll") for (int rm = 0; rm < 4; ++rm)                           \
    _Pragma("unroll") for (int rn = 0; rn < 2; ++rn)                           \
    _Pragma("unroll") for (int kk = 0; kk < 2; ++kk)                           \
      acc[(a) * 4 + rm][(b) * 2 + rn] = __builtin_amdgcn_mfma_f32_16x16x32_bf16( \
          af[rm][kk], bfv[rn][kk], acc[(a) * 4 + rm][(b) * 2 + rn], 0, 0, 0);  \
    __builtin_amdgcn_s_setprio(0);                                             \
  }

#define BAR() __builtin_amdgcn_s_barrier()
#define LGKM0() asm volatile("s_waitcnt lgkmcnt(0)" ::: "memory")
#define SBAR0() __builtin_amdgcn_sched_barrier(0)

#define PHASE(BUFL, RD, STAGE, MA, MB)                                         \
  {                                                                            \
    RD;                                                                        \
    STAGE;                                                                     \
    SBAR0();                                                                   \
    BAR(); LGKM0(); SBAR0();                                                   \
    MMA(MA, MB);                                                               \
    BAR();                                                                     \
  }

#define KT_BODY(BUFL, ktv)                                                     \
  {                                                                            \
    const int kt_ = (ktv);                                                     \
    const int kn1 = (kt_ + 1) & 15, kn2 = (kt_ + 2) & 15;                      \
    asm volatile("s_waitcnt vmcnt(4)" ::: "memory");                           \
    BAR();                                                                     \
    PHASE(BUFL, READ_A(BUFL, 0); READ_B(BUFL, 0), stA(kn1, 1), 0, 0);          \
    PHASE(BUFL, READ_B(BUFL, 1), stB(kn1, 0), 0, 1);                          \
    PHASE(BUFL, READ_A(BUFL, 1), stA(kn2, 0), 1, 1);                          \
    PHASE(BUFL, READ_B(BUFL, 0), stB(kn2, 1), 1, 0);                          \
  }

__global__ __launch_bounds__(512, 2) void k_gemm(const uint16_t* __restrict__ xb,
                                                 const uint16_t* __restrict__ Wt,
                                                 const uint16_t* __restrict__ Bb,
                                                 const float* __restrict__ xa,
                                                 const int* __restrict__ labels,
                                                 const float* __restrict__ bias,
                                                 float* __restrict__ out) {
  __shared__ __align__(16) uint8_t smem[SMEM_BYTES];
  const int t = threadIdx.x;
  const int wid = t >> 6, lane = t & 63;
  const int wr = wid >> 2, wc = wid & 3;
  const int fr = lane & 15, fq = lane >> 4;
  const int sx = fr & 7;

  // XCD-aware bijective swizzle (nwg = 256, 256 % 8 == 0)
  const int bid = blockIdx.x;
  const int sid = (bid & 7) * 32 + (bid >> 3);
  const int m0 = (sid >> 2) * 256;
  const int n0 = (sid & 3) * 256;

  // stage per-tile token metadata (before pipeline; __syncthreads drains)
  int* lbls = (int*)(smem + LBL_OFF);
  float* xas = (float*)(smem + XAS_OFF);
  if (t < 256) lbls[t] = labels[m0 + t];
  {
    const int r = t >> 1, c = (t & 1) * 4;
    *(float4*)(xas + r * 8 + c) = *(const float4*)(xa + (size_t)(m0 + r) * 8 + c);
  }
  __syncthreads();

  // per-thread LDS read bases (kk=0 / kk=1 slot variants)
  lds_ptr_t baseA0 = (lds_ptr_t)(smem + ABUF_OFF + (wr * 16 + fr) * 128 + ((0 + fq) ^ sx) * 16);
  lds_ptr_t baseA1 = (lds_ptr_t)(smem + ABUF_OFF + (wr * 16 + fr) * 128 + ((4 + fq) ^ sx) * 16);
  lds_ptr_t baseB0 = (lds_ptr_t)(smem + BBUF_OFF + (wc * 16 + fr) * 128 + ((0 + fq) ^ sx) * 16);
  lds_ptr_t baseB1 = (lds_ptr_t)(smem + BBUF_OFF + (wc * 16 + fr) * 128 + ((4 + fq) ^ sx) * 16);

  // staging: per call a wave stages 8 rows (1024B linear LDS); 2 calls = half-tile
  const int srow = wid * 8 + (lane >> 3);                    // row in 64-row chunk
  const int sslot = ((lane & 7) ^ ((lane >> 3) & 7)) * 8;    // inverse-swizzled src
  auto stA = [&](int kt, int h) {
    const int buf = kt & 1;
    const uint16_t* g = xb + (size_t)(m0 + h * 128 + srow) * D_DIM + kt * 64 + sslot;
    uint8_t* l = smem + ABUF_OFF + buf * 32768 + h * 16384 + wid * 1024;
    gld_lds16(g, l);
    gld_lds16(g + (size_t)64 * D_DIM, l + 8192);
  };
  auto stB = [&](int kt, int h) {
    const int buf = kt & 1;
    const uint16_t* g = Wt + (size_t)(n0 + h * 128 + srow) * D_DIM + kt * 64 + sslot;
    uint8_t* l = smem + BBUF_OFF + buf * 32768 + h * 16384 + wid * 1024;
    gld_lds16(g, l);
    gld_lds16(g + (size_t)64 * D_DIM, l + 8192);
  };

  f32x4 acc[8][4] = {};
  bf16x8 af[4][2], bfv[2][2];

  // prologue: A0(0), B1(0), A1(0), B0(0), A0(1), B1(1)  (12 loads/thread)
  stA(0, 0); stB(0, 1); stA(0, 1); stB(0, 0); stA(1, 0); stB(1, 1);
  SBAR0();

  for (int ktp = 0; ktp < 8; ++ktp) {
    KT_BODY(0, ktp * 2);
    KT_BODY(1, ktp * 2 + 1);
  }

  // epilogue: out = acc + bias + SCALE * (xa . Bb[lbl][n][:])
  float bv[4];
#pragma unroll
  for (int rn = 0; rn < 4; ++rn) bv[rn] = bias[n0 + rn * 64 + wc * 16 + fr];

#pragma unroll
  for (int rm = 0; rm < 8; ++rm) {
#pragma unroll
    for (int j = 0; j < 4; ++j) {
      const int ml = rm * 32 + wr * 16 + fq * 4 + j;  // C/D row mapping
      const int grow = m0 + ml;
      const int lbl = lbls[ml];
      const float* xv = xas + ml * 8;
      const float x0 = xv[0], x1 = xv[1], x2 = xv[2], x3 = xv[3];
      const float x4 = xv[4], x5 = xv[5], x6 = xv[6], x7 = xv[7];
#pragma unroll
      for (int rn = 0; rn < 4; ++rn) {
        const int n = n0 + rn * 64 + wc * 16 + fr;    // C/D col mapping
        const bf16x8 bb = *(const bf16x8*)(Bb + ((size_t)lbl * D_DIM + n) * 8);
        float dot = x0 * (float)bb[0] + x1 * (float)bb[1] + x2 * (float)bb[2] +
                    x3 * (float)bb[3] + x4 * (float)bb[4] + x5 * (float)bb[5] +
                    x6 * (float)bb[6] + x7 * (float)bb[7];
        out[(size_t)grow * D_DIM + n] = acc[rm][rn][j] + bv[rn] + SCALE * dot;
      }
    }
  }
}

extern "C" void kernel_launch(void* const* d_in, const int* in_sizes, int n_in,
                              void* d_out, int out_size, void* d_ws, size_t ws_size,
                              hipStream_t stream) {
  (void)in_sizes; (void)n_in; (void)out_size; (void)ws_size;
  const float* x      = (const float*)d_in[0];
  const int*   labels = (const int*)d_in[1];
  const float* W      = (const float*)d_in[2];
  const float* A      = (const float*)d_in[3];
  const float* B      = (const float*)d_in[4];
  const float* bias   = (const float*)d_in[5];
  float* out = (float*)d_out;

  uint8_t* ws = (uint8_t*)d_ws;
  uint16_t* xb = (uint16_t*)ws;                          // 33,554,432 B
  uint16_t* Wt = (uint16_t*)(ws + (size_t)33554432);     //  2,097,152 B
  uint16_t* Bb = (uint16_t*)(ws + (size_t)35651584);     //  1,048,576 B
  float*    xa = (float*)   (ws + (size_t)36700160);     //    524,288 B
  uint16_t* At = (uint16_t*)(ws + (size_t)37224448);     //  1,048,576 B

  k_prep_w<<<dim3(32, 32), 256, 0, stream>>>(W, Wt);
  k_prep_b<<<256, 256, 0, stream>>>(B, Bb);
  k_prep_a<<<256, 256, 0, stream>>>(A, At);
  k_prep_x<<<4096, 256, 0, stream>>>(x, labels, At, xb, xa);
  k_gemm<<<256, 512, 0, stream>>>(xb, Wt, Bb, xa, labels, bias, out);
}